// Round 10
// baseline (145.797 us; speedup 1.0000x reference)
//
#include <hip/hip_runtime.h>
#include <hip/hip_bf16.h>
#include <stdint.h>

#define BB 4
#define NN 2048
#define FF 128

typedef __attribute__((ext_vector_type(8))) short bf16x8;
typedef __attribute__((ext_vector_type(4))) float f32x4;

__device__ inline unsigned pk_bf16(float a, float b) {
    union { float f; unsigned u; } x, y;
    x.f = a; y.f = b;
    unsigned xu = x.u + (0x7fffu + ((x.u >> 16) & 1u));
    unsigned yu = y.u + (0x7fffu + ((y.u >> 16) & 1u));
    return (xu >> 16) | (yu & 0xffff0000u);
}

#define XT_P 136
#define WT_P 136

// ---------------- Kernel 1: h = x@W via bf16 MFMA, s = h@a_w + a_b, Ht bf16 ---------
// (unchanged — verified)
__global__ __launch_bounds__(256) void k1_proj(
    const float* __restrict__ x, const float* __restrict__ W,
    const float* __restrict__ a_w, const float* __restrict__ a_b,
    uint16_t* __restrict__ Ht, float* __restrict__ s_out)
{
    __shared__ uint16_t xt[16 * XT_P];
    __shared__ uint16_t Wt[128 * WT_P];
    __shared__ float sredw[4 * 16];

    const int t = threadIdx.x;
    const int w = t >> 6, l = t & 63;
    const int m16 = l & 15, q = l >> 4;
    const int b = blockIdx.x >> 7;
    const int n0 = (blockIdx.x & 127) << 4;

    const int c4 = (t & 31) * 4, kh = (t >> 5) * 16;
    float4 wr0[8], wr1[8];
    #pragma unroll
    for (int kk = 0; kk < 8; ++kk) {
        const int k = kh + 2 * kk;
        wr0[kk] = *(const float4*)(W + (size_t)k * 128 + c4);
        wr1[kk] = *(const float4*)(W + (size_t)(k + 1) * 128 + c4);
    }
    {
        const int row = t >> 4, c0 = (t & 15) * 8;
        const float* xr = x + ((size_t)(b * NN + n0 + row)) * FF + c0;
        const float4 v0 = *(const float4*)xr;
        const float4 v1 = *(const float4*)(xr + 4);
        unsigned* dst = (unsigned*)(xt + row * XT_P + c0);
        dst[0] = pk_bf16(v0.x, v0.y); dst[1] = pk_bf16(v0.z, v0.w);
        dst[2] = pk_bf16(v1.x, v1.y); dst[3] = pk_bf16(v1.z, v1.w);
    }
    #pragma unroll
    for (int kk = 0; kk < 8; ++kk) {
        const int k = kh + 2 * kk;
        *(unsigned*)(Wt + (c4 + 0) * WT_P + k) = pk_bf16(wr0[kk].x, wr1[kk].x);
        *(unsigned*)(Wt + (c4 + 1) * WT_P + k) = pk_bf16(wr0[kk].y, wr1[kk].y);
        *(unsigned*)(Wt + (c4 + 2) * WT_P + k) = pk_bf16(wr0[kk].z, wr1[kk].z);
        *(unsigned*)(Wt + (c4 + 3) * WT_P + k) = pk_bf16(wr0[kk].w, wr1[kk].w);
    }
    const int g0 = (2 * w) * 16 + m16, g1 = (2 * w + 1) * 16 + m16;
    const float aw0 = a_w[g0], aw1 = a_w[g1];
    __syncthreads();

    f32x4 acc0 = {}, acc1 = {};
    bf16x8 af[4];
    #pragma unroll
    for (int dk = 0; dk < 4; ++dk)
        af[dk] = *(const bf16x8*)(xt + m16 * XT_P + dk * 32 + q * 8);
    #pragma unroll
    for (int dk = 0; dk < 4; ++dk) {
        bf16x8 b0 = *(const bf16x8*)(Wt + g0 * WT_P + dk * 32 + q * 8);
        bf16x8 b1 = *(const bf16x8*)(Wt + g1 * WT_P + dk * 32 + q * 8);
        acc0 = __builtin_amdgcn_mfma_f32_16x16x32_bf16(af[dk], b0, acc0, 0, 0, 0);
        acc1 = __builtin_amdgcn_mfma_f32_16x16x32_bf16(af[dk], b1, acc1, 0, 0, 0);
    }

    float sp[4];
    #pragma unroll
    for (int r = 0; r < 4; ++r) sp[r] = acc0[r] * aw0 + acc1[r] * aw1;
    #pragma unroll
    for (int off = 1; off < 16; off <<= 1)
        #pragma unroll
        for (int r = 0; r < 4; ++r) sp[r] += __shfl_xor(sp[r], off, 64);
    if (m16 == 0) {
        #pragma unroll
        for (int r = 0; r < 4; ++r) sredw[w * 16 + q * 4 + r] = sp[r];
    }
    {
        uint2 o0 = { pk_bf16(acc0[0], acc0[1]), pk_bf16(acc0[2], acc0[3]) };
        uint2 o1 = { pk_bf16(acc1[0], acc1[1]), pk_bf16(acc1[2], acc1[3]) };
        *(uint2*)(Ht + ((size_t)(b * 128 + g0)) * NN + n0 + q * 4) = o0;
        *(uint2*)(Ht + ((size_t)(b * 128 + g1)) * NN + n0 + q * 4) = o1;
    }
    __syncthreads();
    if (t < 16)
        s_out[b * NN + n0 + t] = sredw[t] + sredw[16 + t] + sredw[32 + t] + sredw[48 + t] + a_b[0];
}

// ---------------- Kernel 2: barrier-free split-K attention (wave-autonomous) --------
// Same verified geometry (512 blocks: js(8) x is(16) x b(4), 256-j window, IRND=8)
// and the R9 g-split output decomposition, but each wave now computes the FULL
// P tile itself (lanes (q,m16) cover all 256 j for row m16: j = ks*32+q*8+e),
// 4x-redundant exp across waves, so P never touches LDS and the main loop has
// ZERO barriers and ZERO cross-wave dependencies — 4 free-running waves/block.
// A consumed k-slice-wise with in-place 1-round-ahead register rotation (af[16],
// 64 VGPR): af[ks] is read, then immediately re-loaded with round r+1's data ->
// issue-to-use distance ~ one full round. 3/4 of A reads hit same-XCD L2 (16KB
// tiles). Osc epilogue is wave-private (lgkmcnt only). po/prs/k3 unchanged.
#define JS 8
#define IRND 8
#define O_RW 36    // f32 stride of O scratch rows: 16B-aligned rows, ~2-way max

__global__ __launch_bounds__(256, 2) void k2_attn(
    const float* __restrict__ A, const uint16_t* __restrict__ Ht,
    const float* __restrict__ s, uint16_t* __restrict__ po,
    float* __restrict__ prs)
{
    __shared__ float Osc[4][16 * O_RW];    // 9 KB wave-private transpose scratch

    const int t = threadIdx.x;
    const int w = t >> 6, l = t & 63;
    const int m16 = l & 15, q = l >> 4;

    const int bx = blockIdx.x;
    const int b  = bx & 3;                 // XCD-pinned batch
    const int js = (bx >> 2) & 7;
    const int is = bx >> 5;
    const int j0 = js * 256;
    const int ibase = is * 128;

    const float* sb = s + b * NN;
    const float* Ab = A + (size_t)b * NN * NN;
    const uint16_t* Hb = Ht + (size_t)b * FF * NN;

    // h-fragments for THIS WAVE'S 32-g slice, all 8 k-slices (64 VGPR, held).
    // (R9-verified addressing.)
    bf16x8 hf0[8], hf1[8];
    #pragma unroll
    for (int ks = 0; ks < 8; ++ks) {
        const int jj = j0 + ks * 32 + q * 8;
        hf0[ks] = *(const bf16x8*)(Hb + (size_t)(w * 32 + m16) * NN + jj);
        hf1[ks] = *(const bf16x8*)(Hb + (size_t)(w * 32 + 16 + m16) * NN + jj);
    }

    // sj base for this lane's j-columns (L1-hot: block working set = 1 KB)
    const float* sjp = sb + j0 + q * 8;

    // round-0 A prefetch: af[2ks],af[2ks+1] = row (ibase+m16), cols ks*32+q*8..
    float4 af[16];
    {
        const float* Ar0 = Ab + (size_t)(ibase + m16) * NN + j0 + q * 8;
        #pragma unroll
        for (int ks = 0; ks < 8; ++ks) {
            af[2 * ks]     = *(const float4*)(Ar0 + ks * 32);
            af[2 * ks + 1] = *(const float4*)(Ar0 + ks * 32 + 4);
        }
    }

    const size_t slice = (size_t)(js * BB + b);

    for (int r = 0; r < IRND; ++r) {
        const int i0r = ibase + r * 16;
        const int i0n = ibase + ((r + 1) & (IRND - 1)) * 16;
        const float* An = Ab + (size_t)(i0n + m16) * NN + j0 + q * 8;  // next round
        const float si = sb[i0r + m16];

        f32x4 acc0 = {0.f, 0.f, 0.f, 0.f}, acc1 = {0.f, 0.f, 0.f, 0.f};
        float rs = 0.f;

        #pragma unroll
        for (int ks = 0; ks < 8; ++ks) {
            // consume this round's A, immediately re-load slot with next round's
            const float4 a0 = af[2 * ks], a1 = af[2 * ks + 1];
            af[2 * ks]     = *(const float4*)(An + ks * 32);
            af[2 * ks + 1] = *(const float4*)(An + ks * 32 + 4);
            const float4 s0 = *(const float4*)(sjp + ks * 32);
            const float4 s1 = *(const float4*)(sjp + ks * 32 + 4);

            const float av[8] = {a0.x,a0.y,a0.z,a0.w, a1.x,a1.y,a1.z,a1.w};
            const float sv[8] = {s0.x,s0.y,s0.z,s0.w, s1.x,s1.y,s1.z,s1.w};
            float p8[8];
            #pragma unroll
            for (int j = 0; j < 8; ++j) {
                float e = si + sv[j];
                e = fmaxf(e, 0.2f * e);           // LeakyReLU(0.2)
                p8[j] = __expf(e + av[j]);
                rs += p8[j];
            }
            union { unsigned u[4]; bf16x8 v; } pa;
            #pragma unroll
            for (int j = 0; j < 4; ++j)
                pa.u[j] = pk_bf16(p8[2 * j], p8[2 * j + 1]);

            acc0 = __builtin_amdgcn_mfma_f32_16x16x32_bf16(pa.v, hf0[ks], acc0, 0, 0, 0);
            acc1 = __builtin_amdgcn_mfma_f32_16x16x32_bf16(pa.v, hf1[ks], acc1, 0, 0, 0);
        }

        // row-sum: reduce over q within wave (identical across waves); w0 stores
        rs += __shfl_xor(rs, 16, 64);
        rs += __shfl_xor(rs, 32, 64);
        if (t < 16) prs[slice * NN + i0r + t] = rs;

        // wave-private transpose scratch -> coalesced po store (no barrier:
        // same-wave ds_write/ds_read ordered by lgkmcnt automatically)
        #pragma unroll
        for (int rr = 0; rr < 4; ++rr) {
            Osc[w][(q * 4 + rr) * O_RW + m16]      = acc0[rr];
            Osc[w][(q * 4 + rr) * O_RW + 16 + m16] = acc1[rr];
        }
        {
            const int row = l >> 2, c0 = (l & 3) * 8;
            const float4 u0 = *(const float4*)&Osc[w][row * O_RW + c0];
            const float4 u1 = *(const float4*)&Osc[w][row * O_RW + c0 + 4];
            uint4 ov = { pk_bf16(u0.x, u0.y), pk_bf16(u0.z, u0.w),
                         pk_bf16(u1.x, u1.y), pk_bf16(u1.z, u1.w) };
            *(uint4*)(po + ((slice * NN + i0r + row) * FF + w * 32 + c0)) = ov;
        }
    }
}

// ---------------- Kernel 3: reduce 8 partials, normalize, bias (vectorized) ---------
// (verified) Thread handles 8 consecutive g: uint4 po loads, float4 stores.
__global__ __launch_bounds__(256) void k3_red(
    const uint16_t* __restrict__ po, const float* __restrict__ prs,
    const float* __restrict__ bias, float* __restrict__ out)
{
    const int gid = blockIdx.x * 256 + threadIdx.x;
    const int g8 = (gid & 15) * 8;
    const int i = (gid >> 4) & (NN - 1);
    const int b = gid >> 15;                       // NN*16 threads per batch

    float v[8] = {0.f,0.f,0.f,0.f,0.f,0.f,0.f,0.f};
    float rsum = 0.f;
    #pragma unroll
    for (int js = 0; js < JS; ++js) {
        const size_t base = (size_t)(js * BB + b) * NN + i;
        const uint4 pv_ = *(const uint4*)(po + base * FF + g8);
        const unsigned uu[4] = {pv_.x, pv_.y, pv_.z, pv_.w};
        #pragma unroll
        for (int k = 0; k < 4; ++k) {
            union { unsigned u; float f; } lo, hi;
            lo.u = uu[k] << 16;
            hi.u = uu[k] & 0xffff0000u;
            v[2 * k]     += lo.f;
            v[2 * k + 1] += hi.f;
        }
        rsum += prs[base];
    }
    const float inv = 1.0f / rsum;
    const float4 b0 = *(const float4*)(bias + g8);
    const float4 b1 = *(const float4*)(bias + g8 + 4);
    float4 o0 = { v[0]*inv + b0.x, v[1]*inv + b0.y, v[2]*inv + b0.z, v[3]*inv + b0.w };
    float4 o1 = { v[4]*inv + b1.x, v[5]*inv + b1.y, v[6]*inv + b1.z, v[7]*inv + b1.w };
    float* op = out + ((size_t)(b * NN + i)) * FF + g8;
    *(float4*)op = o0;
    *(float4*)(op + 4) = o1;
}

extern "C" void kernel_launch(void* const* d_in, const int* in_sizes, int n_in,
                              void* d_out, int out_size, void* d_ws, size_t ws_size,
                              hipStream_t stream) {
    const float* x    = (const float*)d_in[0];
    const float* A    = (const float*)d_in[1];
    const float* W    = (const float*)d_in[2];
    const float* a_w  = (const float*)d_in[3];
    const float* a_b  = (const float*)d_in[4];
    const float* bias = (const float*)d_in[5];
    float* out = (float*)d_out;

    char* ws = (char*)d_ws;
    uint16_t* Ht = (uint16_t*)ws;                                  // 2 MB
    float* s = (float*)(ws + 2 * 1024 * 1024);                     // 32 KB (pad to 64K)
    uint16_t* po = (uint16_t*)(ws + 2 * 1024 * 1024 + 65536);      // 16 MB
    float* prs = (float*)(ws + 2 * 1024 * 1024 + 65536 + (size_t)JS * BB * NN * FF * 2);  // 256 KB

    k1_proj<<<BB * (NN / 16), 256, 0, stream>>>(x, W, a_w, a_b, Ht, s);
    k2_attn<<<JS * 16 * BB, 256, 0, stream>>>(A, Ht, s, po, prs);
    k3_red<<<(BB * NN * FF) / (256 * 8), 256, 0, stream>>>(po, prs, bias, out);
}

// Round 11
// 125.360 us; speedup vs baseline: 1.1630x; 1.1630x over previous
//
#include <hip/hip_runtime.h>
#include <hip/hip_bf16.h>
#include <stdint.h>

#define BB 4
#define NN 2048
#define FF 128

typedef __attribute__((ext_vector_type(8))) short bf16x8;
typedef __attribute__((ext_vector_type(4))) float f32x4;

__device__ inline unsigned pk_bf16(float a, float b) {
    union { float f; unsigned u; } x, y;
    x.f = a; y.f = b;
    unsigned xu = x.u + (0x7fffu + ((x.u >> 16) & 1u));
    unsigned yu = y.u + (0x7fffu + ((y.u >> 16) & 1u));
    return (xu >> 16) | (yu & 0xffff0000u);
}

#define XT_P 136
#define WT_P 136

// ---------------- Kernel 1: h = x@W via bf16 MFMA, s = h@a_w + a_b, Ht bf16 ---------
// (unchanged — verified)
__global__ __launch_bounds__(256) void k1_proj(
    const float* __restrict__ x, const float* __restrict__ W,
    const float* __restrict__ a_w, const float* __restrict__ a_b,
    uint16_t* __restrict__ Ht, float* __restrict__ s_out)
{
    __shared__ uint16_t xt[16 * XT_P];
    __shared__ uint16_t Wt[128 * WT_P];
    __shared__ float sredw[4 * 16];

    const int t = threadIdx.x;
    const int w = t >> 6, l = t & 63;
    const int m16 = l & 15, q = l >> 4;
    const int b = blockIdx.x >> 7;
    const int n0 = (blockIdx.x & 127) << 4;

    const int c4 = (t & 31) * 4, kh = (t >> 5) * 16;
    float4 wr0[8], wr1[8];
    #pragma unroll
    for (int kk = 0; kk < 8; ++kk) {
        const int k = kh + 2 * kk;
        wr0[kk] = *(const float4*)(W + (size_t)k * 128 + c4);
        wr1[kk] = *(const float4*)(W + (size_t)(k + 1) * 128 + c4);
    }
    {
        const int row = t >> 4, c0 = (t & 15) * 8;
        const float* xr = x + ((size_t)(b * NN + n0 + row)) * FF + c0;
        const float4 v0 = *(const float4*)xr;
        const float4 v1 = *(const float4*)(xr + 4);
        unsigned* dst = (unsigned*)(xt + row * XT_P + c0);
        dst[0] = pk_bf16(v0.x, v0.y); dst[1] = pk_bf16(v0.z, v0.w);
        dst[2] = pk_bf16(v1.x, v1.y); dst[3] = pk_bf16(v1.z, v1.w);
    }
    #pragma unroll
    for (int kk = 0; kk < 8; ++kk) {
        const int k = kh + 2 * kk;
        *(unsigned*)(Wt + (c4 + 0) * WT_P + k) = pk_bf16(wr0[kk].x, wr1[kk].x);
        *(unsigned*)(Wt + (c4 + 1) * WT_P + k) = pk_bf16(wr0[kk].y, wr1[kk].y);
        *(unsigned*)(Wt + (c4 + 2) * WT_P + k) = pk_bf16(wr0[kk].z, wr1[kk].z);
        *(unsigned*)(Wt + (c4 + 3) * WT_P + k) = pk_bf16(wr0[kk].w, wr1[kk].w);
    }
    const int g0 = (2 * w) * 16 + m16, g1 = (2 * w + 1) * 16 + m16;
    const float aw0 = a_w[g0], aw1 = a_w[g1];
    __syncthreads();

    f32x4 acc0 = {}, acc1 = {};
    bf16x8 af[4];
    #pragma unroll
    for (int dk = 0; dk < 4; ++dk)
        af[dk] = *(const bf16x8*)(xt + m16 * XT_P + dk * 32 + q * 8);
    #pragma unroll
    for (int dk = 0; dk < 4; ++dk) {
        bf16x8 b0 = *(const bf16x8*)(Wt + g0 * WT_P + dk * 32 + q * 8);
        bf16x8 b1 = *(const bf16x8*)(Wt + g1 * WT_P + dk * 32 + q * 8);
        acc0 = __builtin_amdgcn_mfma_f32_16x16x32_bf16(af[dk], b0, acc0, 0, 0, 0);
        acc1 = __builtin_amdgcn_mfma_f32_16x16x32_bf16(af[dk], b1, acc1, 0, 0, 0);
    }

    float sp[4];
    #pragma unroll
    for (int r = 0; r < 4; ++r) sp[r] = acc0[r] * aw0 + acc1[r] * aw1;
    #pragma unroll
    for (int off = 1; off < 16; off <<= 1)
        #pragma unroll
        for (int r = 0; r < 4; ++r) sp[r] += __shfl_xor(sp[r], off, 64);
    if (m16 == 0) {
        #pragma unroll
        for (int r = 0; r < 4; ++r) sredw[w * 16 + q * 4 + r] = sp[r];
    }
    {
        uint2 o0 = { pk_bf16(acc0[0], acc0[1]), pk_bf16(acc0[2], acc0[3]) };
        uint2 o1 = { pk_bf16(acc1[0], acc1[1]), pk_bf16(acc1[2], acc1[3]) };
        *(uint2*)(Ht + ((size_t)(b * 128 + g0)) * NN + n0 + q * 4) = o0;
        *(uint2*)(Ht + ((size_t)(b * 128 + g1)) * NN + n0 + q * 4) = o1;
    }
    __syncthreads();
    if (t < 16)
        s_out[b * NN + n0 + t] = sredw[t] + sredw[16 + t] + sredw[32 + t] + sredw[48 + t] + a_b[0];
}

// ---------------- Kernel 2: split-K attention, g-split (R9-verified) + 4 blocks/CU --
// R9 structure byte-for-byte (g-split: P shared via LDS once/round, 1 barrier,
// wave-private O epilogue), ONE change: IRND 8->4 with is(32) -> grid 1024
// blocks = 4 blocks/CU, 16 waves/CU (R9 was grid-limited to 8 waves/CU while
// VGPR/LDS allowed 16 — the one untested lever in this structure).
// XCD pinning preserved: b = bx&3, XCD = bx&7 -> each XCD sees one batch.
#define JS 8
#define IRND 4
#define P_RW 132   // u32 stride of P rows: conflict-free b128 pattern
#define O_RW 36    // f32 stride of O scratch rows

__global__ __launch_bounds__(256, 2) void k2_attn(
    const float* __restrict__ A, const uint16_t* __restrict__ Ht,
    const float* __restrict__ s, uint16_t* __restrict__ po,
    float* __restrict__ prs)
{
    __shared__ unsigned Pbuf[2][16 * P_RW];   // 16.5 KB parity-buffered P
    __shared__ float    Osc[4][16 * O_RW];    // 9 KB wave-private transpose scratch
    __shared__ float    rsw[2][4][16];

    const int t = threadIdx.x;
    const int w = t >> 6, l = t & 63;
    const int m16 = l & 15, q = l >> 4;

    const int bx = blockIdx.x;
    const int b  = bx & 3;                 // XCD-pinned batch
    const int js = (bx >> 2) & 7;
    const int is = bx >> 5;                // 0..31
    const int j0 = js * 256;
    const int ibase = is * 64;             // 64 i-rows per block (IRND=4)

    const float* sb = s + b * NN;
    const float* Ab = A + (size_t)b * NN * NN;
    const uint16_t* Hb = Ht + (size_t)b * FF * NN;

    const int jc0 = j0 + w * 32 + q * 8;
    const int jc1 = j0 + (w + 4) * 32 + q * 8;

    // loop-invariant sj (16 values per lane) — verified pattern
    float4 sj00 = *(const float4*)(sb + jc0);
    float4 sj01 = *(const float4*)(sb + jc0 + 4);
    float4 sj10 = *(const float4*)(sb + jc1);
    float4 sj11 = *(const float4*)(sb + jc1 + 4);

    // h-fragments for THIS WAVE'S g-slice [w*32, w*32+32): all 8 k-slices
    bf16x8 hf0[8], hf1[8];
    #pragma unroll
    for (int ks = 0; ks < 8; ++ks) {
        const int jj = j0 + ks * 32 + q * 8;
        hf0[ks] = *(const bf16x8*)(Hb + (size_t)(w * 32 + m16) * NN + jj);
        hf1[ks] = *(const bf16x8*)(Hb + (size_t)(w * 32 + 16 + m16) * NN + jj);
    }

    // round-0 A prefetch (lane: row ibase+m16, its 16 j's) — verified pattern
    const float* Ar = Ab + (size_t)(ibase + m16) * NN;
    float4 a00 = *(const float4*)(Ar + jc0);
    float4 a01 = *(const float4*)(Ar + jc0 + 4);
    float4 a10 = *(const float4*)(Ar + jc1);
    float4 a11 = *(const float4*)(Ar + jc1 + 4);
    float si = sb[ibase + m16];

    const size_t slice = (size_t)(js * BB + b);

    #pragma unroll
    for (int r = 0; r < IRND; ++r) {
        const int i0r = ibase + r * 16;
        const int i0n = ibase + ((r + 1) & (IRND - 1)) * 16;
        const int par = r & 1;

        // prefetch next round's A + si (full-round latency cover; wraps harmlessly)
        const float* An = Ab + (size_t)(i0n + m16) * NN;
        float4 n00 = *(const float4*)(An + jc0);
        float4 n01 = *(const float4*)(An + jc0 + 4);
        float4 n10 = *(const float4*)(An + jc1);
        float4 n11 = *(const float4*)(An + jc1 + 4);
        const float sin_ = sb[i0n + m16];

        // ---- phase P: exp + pack (byte-identical math to verified kernel) ----
        const float svv[16] = {sj00.x,sj00.y,sj00.z,sj00.w, sj01.x,sj01.y,sj01.z,sj01.w,
                               sj10.x,sj10.y,sj10.z,sj10.w, sj11.x,sj11.y,sj11.z,sj11.w};
        const float avv[16] = {a00.x,a00.y,a00.z,a00.w, a01.x,a01.y,a01.z,a01.w,
                               a10.x,a10.y,a10.z,a10.w, a11.x,a11.y,a11.z,a11.w};
        float pv[16]; float rs = 0.f;
        #pragma unroll
        for (int j = 0; j < 16; ++j) {
            float e = si + svv[j];
            e = fmaxf(e, 0.2f * e);               // LeakyReLU(0.2)
            pv[j] = __expf(e + avv[j]);
            rs += pv[j];
        }
        union { unsigned u[4]; uint4 v4; } fa0, fa1;
        #pragma unroll
        for (int j = 0; j < 4; ++j) {
            fa0.u[j] = pk_bf16(pv[2 * j], pv[2 * j + 1]);
            fa1.u[j] = pk_bf16(pv[8 + 2 * j], pv[9 + 2 * j]);
        }
        // write P[row=m16][j-chunks w*4+q and w*4+q+16] (u32 cols = j/2)
        *(uint4*)&Pbuf[par][m16 * P_RW + (w * 4 + q) * 4]        = fa0.v4;
        *(uint4*)&Pbuf[par][m16 * P_RW + (w * 4 + q + 16) * 4]   = fa1.v4;

        // row-sum partials: reduce over q within wave (rows = m16)
        rs += __shfl_xor(rs, 16, 64);
        rs += __shfl_xor(rs, 32, 64);
        if (q == 0) rsw[par][w][m16] = rs;

        asm volatile("s_waitcnt lgkmcnt(0)\n\ts_barrier" ::: "memory");  // 1/round

        // ---- phase M: read P, 16 MFMAs into private 32-g slice ----
        bf16x8 pa[8];
        #pragma unroll
        for (int ks = 0; ks < 8; ++ks)
            pa[ks] = *(const bf16x8*)&Pbuf[par][m16 * P_RW + ks * 16 + q * 4];

        f32x4 acc0 = {0.f, 0.f, 0.f, 0.f}, acc1 = {0.f, 0.f, 0.f, 0.f};
        #pragma unroll
        for (int ks = 0; ks < 8; ++ks) {
            acc0 = __builtin_amdgcn_mfma_f32_16x16x32_bf16(pa[ks], hf0[ks], acc0, 0, 0, 0);
            acc1 = __builtin_amdgcn_mfma_f32_16x16x32_bf16(pa[ks], hf1[ks], acc1, 0, 0, 0);
        }

        // ---- epilogue: wave-private transpose scratch -> coalesced po store ----
        #pragma unroll
        for (int rr = 0; rr < 4; ++rr) {
            Osc[w][(q * 4 + rr) * O_RW + m16]      = acc0[rr];
            Osc[w][(q * 4 + rr) * O_RW + 16 + m16] = acc1[rr];
        }
        {
            const int row = l >> 2, c0 = (l & 3) * 8;
            const float4 u0 = *(const float4*)&Osc[w][row * O_RW + c0];
            const float4 u1 = *(const float4*)&Osc[w][row * O_RW + c0 + 4];
            uint4 ov = { pk_bf16(u0.x, u0.y), pk_bf16(u0.z, u0.w),
                         pk_bf16(u1.x, u1.y), pk_bf16(u1.z, u1.w) };
            *(uint4*)(po + ((slice * NN + i0r + row) * FF + w * 32 + c0)) = ov;
            if (t < 16)
                prs[slice * NN + i0r + t] = rsw[par][0][t] + rsw[par][1][t]
                                          + rsw[par][2][t] + rsw[par][3][t];
        }

        // rotate the 1-round prefetch
        a00 = n00; a01 = n01; a10 = n10; a11 = n11; si = sin_;
    }
}

// ---------------- Kernel 3: reduce 8 partials, normalize, bias (vectorized) ---------
// (verified) Thread handles 8 consecutive g: uint4 po loads, float4 stores.
__global__ __launch_bounds__(256) void k3_red(
    const uint16_t* __restrict__ po, const float* __restrict__ prs,
    const float* __restrict__ bias, float* __restrict__ out)
{
    const int gid = blockIdx.x * 256 + threadIdx.x;
    const int g8 = (gid & 15) * 8;
    const int i = (gid >> 4) & (NN - 1);
    const int b = gid >> 15;                       // NN*16 threads per batch

    float v[8] = {0.f,0.f,0.f,0.f,0.f,0.f,0.f,0.f};
    float rsum = 0.f;
    #pragma unroll
    for (int js = 0; js < JS; ++js) {
        const size_t base = (size_t)(js * BB + b) * NN + i;
        const uint4 pv_ = *(const uint4*)(po + base * FF + g8);
        const unsigned uu[4] = {pv_.x, pv_.y, pv_.z, pv_.w};
        #pragma unroll
        for (int k = 0; k < 4; ++k) {
            union { unsigned u; float f; } lo, hi;
            lo.u = uu[k] << 16;
            hi.u = uu[k] & 0xffff0000u;
            v[2 * k]     += lo.f;
            v[2 * k + 1] += hi.f;
        }
        rsum += prs[base];
    }
    const float inv = 1.0f / rsum;
    const float4 b0 = *(const float4*)(bias + g8);
    const float4 b1 = *(const float4*)(bias + g8 + 4);
    float4 o0 = { v[0]*inv + b0.x, v[1]*inv + b0.y, v[2]*inv + b0.z, v[3]*inv + b0.w };
    float4 o1 = { v[4]*inv + b1.x, v[5]*inv + b1.y, v[6]*inv + b1.z, v[7]*inv + b1.w };
    float* op = out + ((size_t)(b * NN + i)) * FF + g8;
    *(float4*)op = o0;
    *(float4*)(op + 4) = o1;
}

extern "C" void kernel_launch(void* const* d_in, const int* in_sizes, int n_in,
                              void* d_out, int out_size, void* d_ws, size_t ws_size,
                              hipStream_t stream) {
    const float* x    = (const float*)d_in[0];
    const float* A    = (const float*)d_in[1];
    const float* W    = (const float*)d_in[2];
    const float* a_w  = (const float*)d_in[3];
    const float* a_b  = (const float*)d_in[4];
    const float* bias = (const float*)d_in[5];
    float* out = (float*)d_out;

    char* ws = (char*)d_ws;
    uint16_t* Ht = (uint16_t*)ws;                                  // 2 MB
    float* s = (float*)(ws + 2 * 1024 * 1024);                     // 32 KB (pad to 64K)
    uint16_t* po = (uint16_t*)(ws + 2 * 1024 * 1024 + 65536);      // 16 MB
    float* prs = (float*)(ws + 2 * 1024 * 1024 + 65536 + (size_t)JS * BB * NN * FF * 2);  // 256 KB

    k1_proj<<<BB * (NN / 16), 256, 0, stream>>>(x, W, a_w, a_b, Ht, s);
    k2_attn<<<JS * 32 * BB, 256, 0, stream>>>(A, Ht, s, po, prs);
    k3_red<<<(BB * NN * FF) / (256 * 8), 256, 0, stream>>>(po, prs, bias, out);
}

// Round 12
// 122.584 us; speedup vs baseline: 1.1894x; 1.0226x over previous
//
#include <hip/hip_runtime.h>
#include <hip/hip_bf16.h>
#include <stdint.h>

#define BB 4
#define NN 2048
#define FF 128

typedef __attribute__((ext_vector_type(8))) short bf16x8;
typedef __attribute__((ext_vector_type(4))) float f32x4;

__device__ inline unsigned pk_bf16(float a, float b) {
    union { float f; unsigned u; } x, y;
    x.f = a; y.f = b;
    unsigned xu = x.u + (0x7fffu + ((x.u >> 16) & 1u));
    unsigned yu = y.u + (0x7fffu + ((y.u >> 16) & 1u));
    return (xu >> 16) | (yu & 0xffff0000u);
}

#define XT_P 136
#define WT_P 136

// ---------------- Kernel 1: h = x@W via bf16 MFMA, s = h@a_w + a_b, Ht bf16 ---------
// (unchanged — verified)
__global__ __launch_bounds__(256) void k1_proj(
    const float* __restrict__ x, const float* __restrict__ W,
    const float* __restrict__ a_w, const float* __restrict__ a_b,
    uint16_t* __restrict__ Ht, float* __restrict__ s_out)
{
    __shared__ uint16_t xt[16 * XT_P];
    __shared__ uint16_t Wt[128 * WT_P];
    __shared__ float sredw[4 * 16];

    const int t = threadIdx.x;
    const int w = t >> 6, l = t & 63;
    const int m16 = l & 15, q = l >> 4;
    const int b = blockIdx.x >> 7;
    const int n0 = (blockIdx.x & 127) << 4;

    const int c4 = (t & 31) * 4, kh = (t >> 5) * 16;
    float4 wr0[8], wr1[8];
    #pragma unroll
    for (int kk = 0; kk < 8; ++kk) {
        const int k = kh + 2 * kk;
        wr0[kk] = *(const float4*)(W + (size_t)k * 128 + c4);
        wr1[kk] = *(const float4*)(W + (size_t)(k + 1) * 128 + c4);
    }
    {
        const int row = t >> 4, c0 = (t & 15) * 8;
        const float* xr = x + ((size_t)(b * NN + n0 + row)) * FF + c0;
        const float4 v0 = *(const float4*)xr;
        const float4 v1 = *(const float4*)(xr + 4);
        unsigned* dst = (unsigned*)(xt + row * XT_P + c0);
        dst[0] = pk_bf16(v0.x, v0.y); dst[1] = pk_bf16(v0.z, v0.w);
        dst[2] = pk_bf16(v1.x, v1.y); dst[3] = pk_bf16(v1.z, v1.w);
    }
    #pragma unroll
    for (int kk = 0; kk < 8; ++kk) {
        const int k = kh + 2 * kk;
        *(unsigned*)(Wt + (c4 + 0) * WT_P + k) = pk_bf16(wr0[kk].x, wr1[kk].x);
        *(unsigned*)(Wt + (c4 + 1) * WT_P + k) = pk_bf16(wr0[kk].y, wr1[kk].y);
        *(unsigned*)(Wt + (c4 + 2) * WT_P + k) = pk_bf16(wr0[kk].z, wr1[kk].z);
        *(unsigned*)(Wt + (c4 + 3) * WT_P + k) = pk_bf16(wr0[kk].w, wr1[kk].w);
    }
    const int g0 = (2 * w) * 16 + m16, g1 = (2 * w + 1) * 16 + m16;
    const float aw0 = a_w[g0], aw1 = a_w[g1];
    __syncthreads();

    f32x4 acc0 = {}, acc1 = {};
    bf16x8 af[4];
    #pragma unroll
    for (int dk = 0; dk < 4; ++dk)
        af[dk] = *(const bf16x8*)(xt + m16 * XT_P + dk * 32 + q * 8);
    #pragma unroll
    for (int dk = 0; dk < 4; ++dk) {
        bf16x8 b0 = *(const bf16x8*)(Wt + g0 * WT_P + dk * 32 + q * 8);
        bf16x8 b1 = *(const bf16x8*)(Wt + g1 * WT_P + dk * 32 + q * 8);
        acc0 = __builtin_amdgcn_mfma_f32_16x16x32_bf16(af[dk], b0, acc0, 0, 0, 0);
        acc1 = __builtin_amdgcn_mfma_f32_16x16x32_bf16(af[dk], b1, acc1, 0, 0, 0);
    }

    float sp[4];
    #pragma unroll
    for (int r = 0; r < 4; ++r) sp[r] = acc0[r] * aw0 + acc1[r] * aw1;
    #pragma unroll
    for (int off = 1; off < 16; off <<= 1)
        #pragma unroll
        for (int r = 0; r < 4; ++r) sp[r] += __shfl_xor(sp[r], off, 64);
    if (m16 == 0) {
        #pragma unroll
        for (int r = 0; r < 4; ++r) sredw[w * 16 + q * 4 + r] = sp[r];
    }
    {
        uint2 o0 = { pk_bf16(acc0[0], acc0[1]), pk_bf16(acc0[2], acc0[3]) };
        uint2 o1 = { pk_bf16(acc1[0], acc1[1]), pk_bf16(acc1[2], acc1[3]) };
        *(uint2*)(Ht + ((size_t)(b * 128 + g0)) * NN + n0 + q * 4) = o0;
        *(uint2*)(Ht + ((size_t)(b * 128 + g1)) * NN + n0 + q * 4) = o1;
    }
    __syncthreads();
    if (t < 16)
        s_out[b * NN + n0 + t] = sredw[t] + sredw[16 + t] + sredw[32 + t] + sredw[48 + t] + a_b[0];
}

// ---------------- Kernel 2: g-split attention, PHASE-PIPELINED (R9 geometry) --------
// R9 champion structure (512 blocks: js(8) x is(16) x b(4), IRND=8, g-split,
// 1 barrier/round) with the round SOFTWARE-PIPELINED at phase level: iteration r
// executes { phaseM(r): ds_read Pbuf[par] + 16 MFMA + epilogue  ||  phaseP(r+1):
// exp + pack + write Pbuf[par^1] + A(r+2) prefetch } in ONE inter-barrier region,
// so ds_read-P latency, the exp VALU chain, A-load issue and the MFMA pipe all
// overlap (R9 stacked them serially across the barrier). Hazard audit:
//   Pbuf[par]   read@r  / written@r-1 pre-barrier          -> safe (2 bufs)
//   Pbuf[par^1] write@r / last read@r-1 pre-barrier        -> safe
//   rsw         write (r+1)%3, read r%3, reuse 2 barriers later -> safe (3 bufs)
//   Osc         wave-private, lgkmcnt-ordered              -> safe
// Data path (exp math, pack, MFMA mapping, epilogue, po/prs) = R9 byte-identical.
#define JS 8
#define IRND 8
#define P_RW 132   // u32 stride of P rows: conflict-free b128 pattern
#define O_RW 36    // f32 stride of O scratch rows

__global__ __launch_bounds__(256, 2) void k2_attn(
    const float* __restrict__ A, const uint16_t* __restrict__ Ht,
    const float* __restrict__ s, uint16_t* __restrict__ po,
    float* __restrict__ prs)
{
    __shared__ unsigned Pbuf[2][16 * P_RW];   // 16.5 KB parity-buffered P
    __shared__ float    Osc[4][16 * O_RW];    // 9 KB wave-private transpose scratch
    __shared__ float    rsw[3][4][16];        // 3-deep: same-region write/read split

    const int t = threadIdx.x;
    const int w = t >> 6, l = t & 63;
    const int m16 = l & 15, q = l >> 4;

    const int bx = blockIdx.x;
    const int b  = bx & 3;                 // XCD-pinned batch
    const int js = (bx >> 2) & 7;
    const int is = bx >> 5;                // 0..15
    const int j0 = js * 256;
    const int ibase = is * 128;

    const float* sb = s + b * NN;
    const float* Ab = A + (size_t)b * NN * NN;
    const uint16_t* Hb = Ht + (size_t)b * FF * NN;

    const int jc0 = j0 + w * 32 + q * 8;
    const int jc1 = j0 + (w + 4) * 32 + q * 8;

    // loop-invariant sj (16 values per lane) — verified pattern
    float4 sj00 = *(const float4*)(sb + jc0);
    float4 sj01 = *(const float4*)(sb + jc0 + 4);
    float4 sj10 = *(const float4*)(sb + jc1);
    float4 sj11 = *(const float4*)(sb + jc1 + 4);

    // h-fragments for THIS WAVE'S g-slice [w*32, w*32+32): all 8 k-slices
    bf16x8 hf0[8], hf1[8];
    #pragma unroll
    for (int ks = 0; ks < 8; ++ks) {
        const int jj = j0 + ks * 32 + q * 8;
        hf0[ks] = *(const bf16x8*)(Hb + (size_t)(w * 32 + m16) * NN + jj);
        hf1[ks] = *(const bf16x8*)(Hb + (size_t)(w * 32 + 16 + m16) * NN + jj);
    }

    // all 8 rounds' si up front (8 VGPR, static indexing under full unroll)
    float si_all[IRND];
    #pragma unroll
    for (int rr = 0; rr < IRND; ++rr) si_all[rr] = sb[ibase + rr * 16 + m16];

    // A(0) load
    const float* Ar0 = Ab + (size_t)(ibase + m16) * NN;
    float4 a00 = *(const float4*)(Ar0 + jc0);
    float4 a01 = *(const float4*)(Ar0 + jc0 + 4);
    float4 a10 = *(const float4*)(Ar0 + jc1);
    float4 a11 = *(const float4*)(Ar0 + jc1 + 4);

    // ---- prologue: phaseP(0) -> Pbuf[0], rsw[0] ----
    {
        const float svv[16] = {sj00.x,sj00.y,sj00.z,sj00.w, sj01.x,sj01.y,sj01.z,sj01.w,
                               sj10.x,sj10.y,sj10.z,sj10.w, sj11.x,sj11.y,sj11.z,sj11.w};
        const float avv[16] = {a00.x,a00.y,a00.z,a00.w, a01.x,a01.y,a01.z,a01.w,
                               a10.x,a10.y,a10.z,a10.w, a11.x,a11.y,a11.z,a11.w};
        float pv[16]; float rs = 0.f;
        #pragma unroll
        for (int j = 0; j < 16; ++j) {
            float e = si_all[0] + svv[j];
            e = fmaxf(e, 0.2f * e);
            pv[j] = __expf(e + avv[j]);
            rs += pv[j];
        }
        union { unsigned u[4]; uint4 v4; } fa0, fa1;
        #pragma unroll
        for (int j = 0; j < 4; ++j) {
            fa0.u[j] = pk_bf16(pv[2 * j], pv[2 * j + 1]);
            fa1.u[j] = pk_bf16(pv[8 + 2 * j], pv[9 + 2 * j]);
        }
        *(uint4*)&Pbuf[0][m16 * P_RW + (w * 4 + q) * 4]      = fa0.v4;
        *(uint4*)&Pbuf[0][m16 * P_RW + (w * 4 + q + 16) * 4] = fa1.v4;
        rs += __shfl_xor(rs, 16, 64);
        rs += __shfl_xor(rs, 32, 64);
        if (q == 0) rsw[0][w][m16] = rs;
    }
    // A(1) load (consumed by phaseP(1) inside iteration 0)
    {
        const float* An = Ab + (size_t)(ibase + 16 + m16) * NN;
        a00 = *(const float4*)(An + jc0);
        a01 = *(const float4*)(An + jc0 + 4);
        a10 = *(const float4*)(An + jc1);
        a11 = *(const float4*)(An + jc1 + 4);
    }
    asm volatile("s_waitcnt lgkmcnt(0)\n\ts_barrier" ::: "memory");

    const size_t slice = (size_t)(js * BB + b);

    #pragma unroll
    for (int r = 0; r < IRND; ++r) {
        const int i0r = ibase + r * 16;
        const int par = r & 1;

        // --- phaseM(r) read issue: ds_read P early (latency under phaseP) ---
        bf16x8 pa[8];
        #pragma unroll
        for (int ks = 0; ks < 8; ++ks)
            pa[ks] = *(const bf16x8*)&Pbuf[par][m16 * P_RW + ks * 16 + q * 4];

        // --- phaseP(r+1): exp + pack + write Pbuf[par^1] + A(r+2) prefetch ---
        if (r < IRND - 1) {
            const float svv[16] = {sj00.x,sj00.y,sj00.z,sj00.w, sj01.x,sj01.y,sj01.z,sj01.w,
                                   sj10.x,sj10.y,sj10.z,sj10.w, sj11.x,sj11.y,sj11.z,sj11.w};
            const float avv[16] = {a00.x,a00.y,a00.z,a00.w, a01.x,a01.y,a01.z,a01.w,
                                   a10.x,a10.y,a10.z,a10.w, a11.x,a11.y,a11.z,a11.w};
            float pv[16]; float rs = 0.f;
            #pragma unroll
            for (int j = 0; j < 16; ++j) {
                float e = si_all[r + 1] + svv[j];
                e = fmaxf(e, 0.2f * e);               // LeakyReLU(0.2)
                pv[j] = __expf(e + avv[j]);
                rs += pv[j];
            }
            union { unsigned u[4]; uint4 v4; } fa0, fa1;
            #pragma unroll
            for (int j = 0; j < 4; ++j) {
                fa0.u[j] = pk_bf16(pv[2 * j], pv[2 * j + 1]);
                fa1.u[j] = pk_bf16(pv[8 + 2 * j], pv[9 + 2 * j]);
            }
            *(uint4*)&Pbuf[par ^ 1][m16 * P_RW + (w * 4 + q) * 4]      = fa0.v4;
            *(uint4*)&Pbuf[par ^ 1][m16 * P_RW + (w * 4 + q + 16) * 4] = fa1.v4;
            rs += __shfl_xor(rs, 16, 64);
            rs += __shfl_xor(rs, 32, 64);
            if (q == 0) rsw[(r + 1) % 3][w][m16] = rs;

            // prefetch A(r+2) (wraps harmlessly on the last rounds)
            const int i2 = ibase + ((r + 2) & (IRND - 1)) * 16;
            const float* An = Ab + (size_t)(i2 + m16) * NN;
            a00 = *(const float4*)(An + jc0);
            a01 = *(const float4*)(An + jc0 + 4);
            a10 = *(const float4*)(An + jc1);
            a11 = *(const float4*)(An + jc1 + 4);
        }

        // --- phaseM(r) compute: 16 MFMAs into private 32-g slice ---
        f32x4 acc0 = {0.f, 0.f, 0.f, 0.f}, acc1 = {0.f, 0.f, 0.f, 0.f};
        #pragma unroll
        for (int ks = 0; ks < 8; ++ks) {
            acc0 = __builtin_amdgcn_mfma_f32_16x16x32_bf16(pa[ks], hf0[ks], acc0, 0, 0, 0);
            acc1 = __builtin_amdgcn_mfma_f32_16x16x32_bf16(pa[ks], hf1[ks], acc1, 0, 0, 0);
        }

        // --- epilogue: wave-private transpose scratch -> coalesced po store ---
        #pragma unroll
        for (int rr = 0; rr < 4; ++rr) {
            Osc[w][(q * 4 + rr) * O_RW + m16]      = acc0[rr];
            Osc[w][(q * 4 + rr) * O_RW + 16 + m16] = acc1[rr];
        }
        {
            const int row = l >> 2, c0 = (l & 3) * 8;
            const float4 u0 = *(const float4*)&Osc[w][row * O_RW + c0];
            const float4 u1 = *(const float4*)&Osc[w][row * O_RW + c0 + 4];
            uint4 ov = { pk_bf16(u0.x, u0.y), pk_bf16(u0.z, u0.w),
                         pk_bf16(u1.x, u1.y), pk_bf16(u1.z, u1.w) };
            *(uint4*)(po + ((slice * NN + i0r + row) * FF + w * 32 + c0)) = ov;
            if (t < 16)
                prs[slice * NN + i0r + t] = rsw[r % 3][0][t] + rsw[r % 3][1][t]
                                          + rsw[r % 3][2][t] + rsw[r % 3][3][t];
        }

        asm volatile("s_waitcnt lgkmcnt(0)\n\ts_barrier" ::: "memory");  // 1/round
    }
}

// ---------------- Kernel 3: reduce 8 partials, normalize, bias (vectorized) ---------
// (verified) Thread handles 8 consecutive g: uint4 po loads, float4 stores.
__global__ __launch_bounds__(256) void k3_red(
    const uint16_t* __restrict__ po, const float* __restrict__ prs,
    const float* __restrict__ bias, float* __restrict__ out)
{
    const int gid = blockIdx.x * 256 + threadIdx.x;
    const int g8 = (gid & 15) * 8;
    const int i = (gid >> 4) & (NN - 1);
    const int b = gid >> 15;                       // NN*16 threads per batch

    float v[8] = {0.f,0.f,0.f,0.f,0.f,0.f,0.f,0.f};
    float rsum = 0.f;
    #pragma unroll
    for (int js = 0; js < JS; ++js) {
        const size_t base = (size_t)(js * BB + b) * NN + i;
        const uint4 pv_ = *(const uint4*)(po + base * FF + g8);
        const unsigned uu[4] = {pv_.x, pv_.y, pv_.z, pv_.w};
        #pragma unroll
        for (int k = 0; k < 4; ++k) {
            union { unsigned u; float f; } lo, hi;
            lo.u = uu[k] << 16;
            hi.u = uu[k] & 0xffff0000u;
            v[2 * k]     += lo.f;
            v[2 * k + 1] += hi.f;
        }
        rsum += prs[base];
    }
    const float inv = 1.0f / rsum;
    const float4 b0 = *(const float4*)(bias + g8);
    const float4 b1 = *(const float4*)(bias + g8 + 4);
    float4 o0 = { v[0]*inv + b0.x, v[1]*inv + b0.y, v[2]*inv + b0.z, v[3]*inv + b0.w };
    float4 o1 = { v[4]*inv + b1.x, v[5]*inv + b1.y, v[6]*inv + b1.z, v[7]*inv + b1.w };
    float* op = out + ((size_t)(b * NN + i)) * FF + g8;
    *(float4*)op = o0;
    *(float4*)(op + 4) = o1;
}

extern "C" void kernel_launch(void* const* d_in, const int* in_sizes, int n_in,
                              void* d_out, int out_size, void* d_ws, size_t ws_size,
                              hipStream_t stream) {
    const float* x    = (const float*)d_in[0];
    const float* A    = (const float*)d_in[1];
    const float* W    = (const float*)d_in[2];
    const float* a_w  = (const float*)d_in[3];
    const float* a_b  = (const float*)d_in[4];
    const float* bias = (const float*)d_in[5];
    float* out = (float*)d_out;

    char* ws = (char*)d_ws;
    uint16_t* Ht = (uint16_t*)ws;                                  // 2 MB
    float* s = (float*)(ws + 2 * 1024 * 1024);                     // 32 KB (pad to 64K)
    uint16_t* po = (uint16_t*)(ws + 2 * 1024 * 1024 + 65536);      // 16 MB
    float* prs = (float*)(ws + 2 * 1024 * 1024 + 65536 + (size_t)JS * BB * NN * FF * 2);  // 256 KB

    k1_proj<<<BB * (NN / 16), 256, 0, stream>>>(x, W, a_w, a_b, Ht, s);
    k2_attn<<<JS * 16 * BB, 256, 0, stream>>>(A, Ht, s, po, prs);
    k3_red<<<(BB * NN * FF) / (256 * 8), 256, 0, stream>>>(po, prs, bias, out);
}

// Round 13
// 120.688 us; speedup vs baseline: 1.2080x; 1.0157x over previous
//
#include <hip/hip_runtime.h>
#include <hip/hip_bf16.h>
#include <stdint.h>

#define BB 4
#define NN 2048
#define FF 128

typedef __attribute__((ext_vector_type(8))) short bf16x8;
typedef __attribute__((ext_vector_type(4))) float f32x4;

__device__ inline unsigned pk_bf16(float a, float b) {
    union { float f; unsigned u; } x, y;
    x.f = a; y.f = b;
    unsigned xu = x.u + (0x7fffu + ((x.u >> 16) & 1u));
    unsigned yu = y.u + (0x7fffu + ((y.u >> 16) & 1u));
    return (xu >> 16) | (yu & 0xffff0000u);
}

#define XT_P 136
#define WT_P 136

// ---------------- Kernel 1: h = x@W via bf16 MFMA, s = h@a_w + a_b, Ht bf16 ---------
// (unchanged — verified)
__global__ __launch_bounds__(256) void k1_proj(
    const float* __restrict__ x, const float* __restrict__ W,
    const float* __restrict__ a_w, const float* __restrict__ a_b,
    uint16_t* __restrict__ Ht, float* __restrict__ s_out)
{
    __shared__ uint16_t xt[16 * XT_P];
    __shared__ uint16_t Wt[128 * WT_P];
    __shared__ float sredw[4 * 16];

    const int t = threadIdx.x;
    const int w = t >> 6, l = t & 63;
    const int m16 = l & 15, q = l >> 4;
    const int b = blockIdx.x >> 7;
    const int n0 = (blockIdx.x & 127) << 4;

    const int c4 = (t & 31) * 4, kh = (t >> 5) * 16;
    float4 wr0[8], wr1[8];
    #pragma unroll
    for (int kk = 0; kk < 8; ++kk) {
        const int k = kh + 2 * kk;
        wr0[kk] = *(const float4*)(W + (size_t)k * 128 + c4);
        wr1[kk] = *(const float4*)(W + (size_t)(k + 1) * 128 + c4);
    }
    {
        const int row = t >> 4, c0 = (t & 15) * 8;
        const float* xr = x + ((size_t)(b * NN + n0 + row)) * FF + c0;
        const float4 v0 = *(const float4*)xr;
        const float4 v1 = *(const float4*)(xr + 4);
        unsigned* dst = (unsigned*)(xt + row * XT_P + c0);
        dst[0] = pk_bf16(v0.x, v0.y); dst[1] = pk_bf16(v0.z, v0.w);
        dst[2] = pk_bf16(v1.x, v1.y); dst[3] = pk_bf16(v1.z, v1.w);
    }
    #pragma unroll
    for (int kk = 0; kk < 8; ++kk) {
        const int k = kh + 2 * kk;
        *(unsigned*)(Wt + (c4 + 0) * WT_P + k) = pk_bf16(wr0[kk].x, wr1[kk].x);
        *(unsigned*)(Wt + (c4 + 1) * WT_P + k) = pk_bf16(wr0[kk].y, wr1[kk].y);
        *(unsigned*)(Wt + (c4 + 2) * WT_P + k) = pk_bf16(wr0[kk].z, wr1[kk].z);
        *(unsigned*)(Wt + (c4 + 3) * WT_P + k) = pk_bf16(wr0[kk].w, wr1[kk].w);
    }
    const int g0 = (2 * w) * 16 + m16, g1 = (2 * w + 1) * 16 + m16;
    const float aw0 = a_w[g0], aw1 = a_w[g1];
    __syncthreads();

    f32x4 acc0 = {}, acc1 = {};
    bf16x8 af[4];
    #pragma unroll
    for (int dk = 0; dk < 4; ++dk)
        af[dk] = *(const bf16x8*)(xt + m16 * XT_P + dk * 32 + q * 8);
    #pragma unroll
    for (int dk = 0; dk < 4; ++dk) {
        bf16x8 b0 = *(const bf16x8*)(Wt + g0 * WT_P + dk * 32 + q * 8);
        bf16x8 b1 = *(const bf16x8*)(Wt + g1 * WT_P + dk * 32 + q * 8);
        acc0 = __builtin_amdgcn_mfma_f32_16x16x32_bf16(af[dk], b0, acc0, 0, 0, 0);
        acc1 = __builtin_amdgcn_mfma_f32_16x16x32_bf16(af[dk], b1, acc1, 0, 0, 0);
    }

    float sp[4];
    #pragma unroll
    for (int r = 0; r < 4; ++r) sp[r] = acc0[r] * aw0 + acc1[r] * aw1;
    #pragma unroll
    for (int off = 1; off < 16; off <<= 1)
        #pragma unroll
        for (int r = 0; r < 4; ++r) sp[r] += __shfl_xor(sp[r], off, 64);
    if (m16 == 0) {
        #pragma unroll
        for (int r = 0; r < 4; ++r) sredw[w * 16 + q * 4 + r] = sp[r];
    }
    {
        uint2 o0 = { pk_bf16(acc0[0], acc0[1]), pk_bf16(acc0[2], acc0[3]) };
        uint2 o1 = { pk_bf16(acc1[0], acc1[1]), pk_bf16(acc1[2], acc1[3]) };
        *(uint2*)(Ht + ((size_t)(b * 128 + g0)) * NN + n0 + q * 4) = o0;
        *(uint2*)(Ht + ((size_t)(b * 128 + g1)) * NN + n0 + q * 4) = o1;
    }
    __syncthreads();
    if (t < 16)
        s_out[b * NN + n0 + t] = sredw[t] + sredw[16 + t] + sredw[32 + t] + sredw[48 + t] + a_b[0];
}

// ---------------- Kernel 2: split-K attention, g-split (R9 CHAMPION, restored) ------
// Best-measured structure (119.97 us total). Per round:
//   phase P: all waves compute P (verified exp/pack math) -> LDS (parity buffer);
//            rs reduced into parity rsw. ONE barrier (lgkm-only drain).
//   phase M: each wave reads the P tile (8 x ds_read_b128) and computes its
//            PRIVATE 32-g output slice (16 MFMAs). No cross-wave O reduce.
//   epilogue: wave-private LDS transpose scratch -> pk_bf16 -> coalesced b128
//            po store; prs from parity rsw.
// A streamed with 1-round register prefetch. b = bx&3 pins batches to XCDs.
#define JS 8
#define IRND 8
#define P_RW 132   // u32 stride of P rows: conflict-free b128 pattern
#define O_RW 36    // f32 stride of O scratch rows

__global__ __launch_bounds__(256, 2) void k2_attn(
    const float* __restrict__ A, const uint16_t* __restrict__ Ht,
    const float* __restrict__ s, uint16_t* __restrict__ po,
    float* __restrict__ prs)
{
    __shared__ unsigned Pbuf[2][16 * P_RW];   // 16.5 KB parity-buffered P
    __shared__ float    Osc[4][16 * O_RW];    // 9 KB wave-private transpose scratch
    __shared__ float    rsw[2][4][16];

    const int t = threadIdx.x;
    const int w = t >> 6, l = t & 63;
    const int m16 = l & 15, q = l >> 4;

    const int bx = blockIdx.x;
    const int b  = bx & 3;                 // XCD-pinned batch
    const int js = (bx >> 2) & 7;
    const int is = bx >> 5;
    const int j0 = js * 256;
    const int ibase = is * 128;

    const float* sb = s + b * NN;
    const float* Ab = A + (size_t)b * NN * NN;
    const uint16_t* Hb = Ht + (size_t)b * FF * NN;

    const int jc0 = j0 + w * 32 + q * 8;
    const int jc1 = j0 + (w + 4) * 32 + q * 8;

    // loop-invariant sj (16 values per lane) — verified pattern
    float4 sj00 = *(const float4*)(sb + jc0);
    float4 sj01 = *(const float4*)(sb + jc0 + 4);
    float4 sj10 = *(const float4*)(sb + jc1);
    float4 sj11 = *(const float4*)(sb + jc1 + 4);

    // h-fragments for THIS WAVE'S g-slice [w*32, w*32+32): all 8 k-slices
    bf16x8 hf0[8], hf1[8];
    #pragma unroll
    for (int ks = 0; ks < 8; ++ks) {
        const int jj = j0 + ks * 32 + q * 8;
        hf0[ks] = *(const bf16x8*)(Hb + (size_t)(w * 32 + m16) * NN + jj);
        hf1[ks] = *(const bf16x8*)(Hb + (size_t)(w * 32 + 16 + m16) * NN + jj);
    }

    // round-0 A prefetch (lane: row ibase+m16, its 16 j's) — verified pattern
    const float* Ar = Ab + (size_t)(ibase + m16) * NN;
    float4 a00 = *(const float4*)(Ar + jc0);
    float4 a01 = *(const float4*)(Ar + jc0 + 4);
    float4 a10 = *(const float4*)(Ar + jc1);
    float4 a11 = *(const float4*)(Ar + jc1 + 4);
    float si = sb[ibase + m16];

    const size_t slice = (size_t)(js * BB + b);

    #pragma unroll
    for (int r = 0; r < IRND; ++r) {
        const int i0r = ibase + r * 16;
        const int i0n = ibase + ((r + 1) & (IRND - 1)) * 16;
        const int par = r & 1;

        // prefetch next round's A + si (full-round latency cover; wraps harmlessly)
        const float* An = Ab + (size_t)(i0n + m16) * NN;
        float4 n00 = *(const float4*)(An + jc0);
        float4 n01 = *(const float4*)(An + jc0 + 4);
        float4 n10 = *(const float4*)(An + jc1);
        float4 n11 = *(const float4*)(An + jc1 + 4);
        const float sin_ = sb[i0n + m16];

        // ---- phase P: exp + pack (byte-identical math to verified kernel) ----
        const float svv[16] = {sj00.x,sj00.y,sj00.z,sj00.w, sj01.x,sj01.y,sj01.z,sj01.w,
                               sj10.x,sj10.y,sj10.z,sj10.w, sj11.x,sj11.y,sj11.z,sj11.w};
        const float avv[16] = {a00.x,a00.y,a00.z,a00.w, a01.x,a01.y,a01.z,a01.w,
                               a10.x,a10.y,a10.z,a10.w, a11.x,a11.y,a11.z,a11.w};
        float pv[16]; float rs = 0.f;
        #pragma unroll
        for (int j = 0; j < 16; ++j) {
            float e = si + svv[j];
            e = fmaxf(e, 0.2f * e);               // LeakyReLU(0.2)
            pv[j] = __expf(e + avv[j]);
            rs += pv[j];
        }
        union { unsigned u[4]; uint4 v4; } fa0, fa1;
        #pragma unroll
        for (int j = 0; j < 4; ++j) {
            fa0.u[j] = pk_bf16(pv[2 * j], pv[2 * j + 1]);
            fa1.u[j] = pk_bf16(pv[8 + 2 * j], pv[9 + 2 * j]);
        }
        // write P[row=m16][j-chunks w*4+q and w*4+q+16] (u32 cols = j/2)
        *(uint4*)&Pbuf[par][m16 * P_RW + (w * 4 + q) * 4]        = fa0.v4;
        *(uint4*)&Pbuf[par][m16 * P_RW + (w * 4 + q + 16) * 4]   = fa1.v4;

        // row-sum partials: reduce over q within wave (rows = m16)
        rs += __shfl_xor(rs, 16, 64);
        rs += __shfl_xor(rs, 32, 64);
        if (q == 0) rsw[par][w][m16] = rs;

        asm volatile("s_waitcnt lgkmcnt(0)\n\ts_barrier" ::: "memory");  // 1/round

        // ---- phase M: read P, 16 MFMAs into private 32-g slice ----
        bf16x8 pa[8];
        #pragma unroll
        for (int ks = 0; ks < 8; ++ks)
            pa[ks] = *(const bf16x8*)&Pbuf[par][m16 * P_RW + ks * 16 + q * 4];

        f32x4 acc0 = {0.f, 0.f, 0.f, 0.f}, acc1 = {0.f, 0.f, 0.f, 0.f};
        #pragma unroll
        for (int ks = 0; ks < 8; ++ks) {
            acc0 = __builtin_amdgcn_mfma_f32_16x16x32_bf16(pa[ks], hf0[ks], acc0, 0, 0, 0);
            acc1 = __builtin_amdgcn_mfma_f32_16x16x32_bf16(pa[ks], hf1[ks], acc1, 0, 0, 0);
        }

        // ---- epilogue: wave-private transpose scratch -> coalesced po store ----
        // D layout: row i = q*4+reg, col g = (w*32|w*32+16) + m16
        #pragma unroll
        for (int rr = 0; rr < 4; ++rr) {
            Osc[w][(q * 4 + rr) * O_RW + m16]      = acc0[rr];
            Osc[w][(q * 4 + rr) * O_RW + 16 + m16] = acc1[rr];
        }
        {
            const int row = l >> 2, c0 = (l & 3) * 8;
            const float4 u0 = *(const float4*)&Osc[w][row * O_RW + c0];
            const float4 u1 = *(const float4*)&Osc[w][row * O_RW + c0 + 4];
            uint4 ov = { pk_bf16(u0.x, u0.y), pk_bf16(u0.z, u0.w),
                         pk_bf16(u1.x, u1.y), pk_bf16(u1.z, u1.w) };
            *(uint4*)(po + ((slice * NN + i0r + row) * FF + w * 32 + c0)) = ov;
            if (t < 16)
                prs[slice * NN + i0r + t] = rsw[par][0][t] + rsw[par][1][t]
                                          + rsw[par][2][t] + rsw[par][3][t];
        }

        // rotate the 1-round prefetch
        a00 = n00; a01 = n01; a10 = n10; a11 = n11; si = sin_;
    }
}

// ---------------- Kernel 3: reduce 8 partials, normalize, bias (vectorized) ---------
// (verified) Thread handles 8 consecutive g: uint4 po loads, float4 stores.
__global__ __launch_bounds__(256) void k3_red(
    const uint16_t* __restrict__ po, const float* __restrict__ prs,
    const float* __restrict__ bias, float* __restrict__ out)
{
    const int gid = blockIdx.x * 256 + threadIdx.x;
    const int g8 = (gid & 15) * 8;
    const int i = (gid >> 4) & (NN - 1);
    const int b = gid >> 15;                       // NN*16 threads per batch

    float v[8] = {0.f,0.f,0.f,0.f,0.f,0.f,0.f,0.f};
    float rsum = 0.f;
    #pragma unroll
    for (int js = 0; js < JS; ++js) {
        const size_t base = (size_t)(js * BB + b) * NN + i;
        const uint4 pv_ = *(const uint4*)(po + base * FF + g8);
        const unsigned uu[4] = {pv_.x, pv_.y, pv_.z, pv_.w};
        #pragma unroll
        for (int k = 0; k < 4; ++k) {
            union { unsigned u; float f; } lo, hi;
            lo.u = uu[k] << 16;
            hi.u = uu[k] & 0xffff0000u;
            v[2 * k]     += lo.f;
            v[2 * k + 1] += hi.f;
        }
        rsum += prs[base];
    }
    const float inv = 1.0f / rsum;
    const float4 b0 = *(const float4*)(bias + g8);
    const float4 b1 = *(const float4*)(bias + g8 + 4);
    float4 o0 = { v[0]*inv + b0.x, v[1]*inv + b0.y, v[2]*inv + b0.z, v[3]*inv + b0.w };
    float4 o1 = { v[4]*inv + b1.x, v[5]*inv + b1.y, v[6]*inv + b1.z, v[7]*inv + b1.w };
    float* op = out + ((size_t)(b * NN + i)) * FF + g8;
    *(float4*)op = o0;
    *(float4*)(op + 4) = o1;
}

extern "C" void kernel_launch(void* const* d_in, const int* in_sizes, int n_in,
                              void* d_out, int out_size, void* d_ws, size_t ws_size,
                              hipStream_t stream) {
    const float* x    = (const float*)d_in[0];
    const float* A    = (const float*)d_in[1];
    const float* W    = (const float*)d_in[2];
    const float* a_w  = (const float*)d_in[3];
    const float* a_b  = (const float*)d_in[4];
    const float* bias = (const float*)d_in[5];
    float* out = (float*)d_out;

    char* ws = (char*)d_ws;
    uint16_t* Ht = (uint16_t*)ws;                                  // 2 MB
    float* s = (float*)(ws + 2 * 1024 * 1024);                     // 32 KB (pad to 64K)
    uint16_t* po = (uint16_t*)(ws + 2 * 1024 * 1024 + 65536);      // 16 MB
    float* prs = (float*)(ws + 2 * 1024 * 1024 + 65536 + (size_t)JS * BB * NN * FF * 2);  // 256 KB

    k1_proj<<<BB * (NN / 16), 256, 0, stream>>>(x, W, a_w, a_b, Ht, s);
    k2_attn<<<JS * 16 * BB, 256, 0, stream>>>(A, Ht, s, po, prs);
    k3_red<<<(BB * NN * FF) / (256 * 8), 256, 0, stream>>>(po, prs, bias, out);
}